// Round 12
// baseline (328.479 us; speedup 1.0000x reference)
//
#include <hip/hip_runtime.h>
#include <math.h>

#define N_ 8
#define C_ 128
#define T_ 64
#define V_ 204
#define H_ 3
#define QKD_ 32
#define O2_ 192            // 2*H*QKD
#define TV_ 13056          // T*V
#define CT_ 8192           // C*T
#define TT_ 4096           // T*T
#define VV_ 41616          // V*V
#define NCTV_ 13369344ull  // N*C*T*V
#define DSPLIT_ 32
#define ZR_ 208
#define NBLK_ 1632

typedef __attribute__((ext_vector_type(8))) short short8v;
typedef __attribute__((ext_vector_type(4))) float f32x4;

__device__ inline unsigned short bf16rnd(float f) {
  union { float f; unsigned u; } x; x.f = f;
  return (unsigned short)((x.u + 0x7FFFu + ((x.u >> 16) & 1u)) >> 16);
}
__device__ inline float bf2f(unsigned short u) {
  union { unsigned u; float f; } x; x.u = ((unsigned)u) << 16;
  return x.f;
}
// async global->LDS 16B (dest = wave-uniform base + lane*16; src per-lane)
__device__ inline void gload_lds16(const unsigned short* g, unsigned short* l) {
  __builtin_amdgcn_global_load_lds((const __attribute__((address_space(1))) void*)g,
                                   (__attribute__((address_space(3))) void*)l, 16, 0, 0);
}

// ---- weights -> bf16 rows [m][128]: qkv_wb(192) | w3b(384: [h][o]) | ff_wb(128) ----
__global__ void k_wprep(const float* __restrict__ qw, const float* __restrict__ ow,
                        const float* __restrict__ fw, unsigned short* __restrict__ wb) {
  int g = blockIdx.x * 256 + threadIdx.x;
  if (g >= 704 * 16) return;
  int row = g >> 4, ch = g & 15;
  const float* src;
  if (row < 192) src = qw + row * 128;
  else if (row < 576) { int r = row - 192; src = ow + (r & 127) * 384 + (r >> 7) * 128; }
  else src = fw + (row - 576) * 128;
  f32x4 a = *(const f32x4*)(src + ch * 8);
  f32x4 b = *(const f32x4*)(src + ch * 8 + 4);
  unsigned short buf[8];
  buf[0] = bf16rnd(a.x); buf[1] = bf16rnd(a.y); buf[2] = bf16rnd(a.z); buf[3] = bf16rnd(a.w);
  buf[4] = bf16rnd(b.x); buf[5] = bf16rnd(b.y); buf[6] = bf16rnd(b.z); buf[7] = bf16rnd(b.w);
  *(uint4*)(wb + (size_t)row * 128 + ch * 8) = *(const uint4*)buf;
}

// ---- qpe[m][t] = qkv_b[m] + sum_c qkv_w[m][c]*pe[c][t] ----
__global__ void k_qkvpe(const float* __restrict__ qw, const float* __restrict__ qb,
                        float* __restrict__ qpe) {
  __shared__ float pes[C_ * T_];
  int tid = threadIdx.x;
  for (int i = tid; i < C_ * T_; i += 256) {
    int t = i & 63, c = i >> 6;
    int j = c >> 1;
    float dv = expf((2.0f * j) * (-logf(10000.0f) / (float)C_));
    float ang = (float)t * dv;
    pes[i] = (c & 1) ? cosf(ang) : sinf(ang);
  }
  __syncthreads();
  int g = blockIdx.x * 256 + tid;
  int t = g & 63, m = g >> 6;
  float a = 0.f;
  for (int c = 0; c < C_; ++c) a += qw[m * C_ + c] * pes[c * T_ + t];
  qpe[g] = a + qb[m];
}

// ---------------- s[n,c,t] = 1/max(||x||,1e-12)^2 ----------------
__global__ void k_scale(const float* __restrict__ x, float* __restrict__ s) {
  int gid = blockIdx.x * blockDim.x + threadIdx.x;
  int w = gid >> 6, lane = gid & 63;
  if (w >= N_ * CT_) return;
  const f32x4* row = (const f32x4*)(x + (size_t)w * V_);
  float a = 0.f;
  for (int v4 = lane; v4 < 51; v4 += 64) {
    f32x4 t = row[v4];
    a += t.x * t.x + t.y * t.y + t.z * t.z + t.w * t.w;
  }
#pragma unroll
  for (int off = 32; off >= 1; off >>= 1) a += __shfl_down(a, off, 64);
  if (lane == 0) {
    float d = fmaxf(sqrtf(a), 1e-12f);
    s[w] = 1.0f / (d * d);
  }
}

// ---- Z-prep: fragment-major bf16 hi/lo + colmean ----
__global__ __launch_bounds__(256) void k_zprep(const float* __restrict__ x,
                                               const float* __restrict__ s,
                                               unsigned short* __restrict__ zhi,
                                               unsigned short* __restrict__ zlo,
                                               float* __restrict__ cm) {
  int kt = blockIdx.x, ut = blockIdx.y, n = blockIdx.z;
  int k0 = kt * 64, u0 = ut * 64;
  __shared__ float Ts[64][65];
  __shared__ float sq[64];
  int tid = threadIdx.x;
  int uu = tid & 63, kk = tid >> 6;
  int u = u0 + uu;
  bool uok = u < V_;
  const float* xb = x + (size_t)n * CT_ * V_;
#pragma unroll
  for (int it = 0; it < 16; ++it) {
    int kr = kk + it * 4;
    Ts[kr][uu] = uok ? xb[(size_t)(k0 + kr) * V_ + u] : 0.f;
  }
  if (tid < 64) sq[tid] = sqrtf(s[(size_t)n * CT_ + k0 + tid]);
  __syncthreads();
  if (tid < 64 && uok) {
    float a = 0.f;
    for (int t = 0; t < 64; ++t) a += Ts[t][tid];
    cm[((size_t)n * C_ + kt) * V_ + u] = a * (1.0f / 64.0f);
  }
#pragma unroll
  for (int it = 0; it < 4; ++it) {
    int sl = tid + it * 256;
    int u_l = sl & 63, oct = (sl >> 6) & 7, half = sl >> 9;
    int ug = u0 + u_l;
    if (ug >= ZR_) continue;
    unsigned short buf[8];
    if (ug < V_) {
#pragma unroll
      for (int j = 0; j < 8; ++j) {
        float z = Ts[oct * 8 + j][u_l] * sq[oct * 8 + j];
        unsigned short h = bf16rnd(z);
        buf[j] = half ? bf16rnd(z - bf2f(h)) : h;
      }
    } else {
#pragma unroll
      for (int j = 0; j < 8; ++j) buf[j] = 0;
    }
    unsigned short* dst = (half ? zlo : zhi) +
                          (((size_t)n * 1024 + kt * 8 + oct) * ZR_ + ug) * 8;
    *(uint4*)dst = *(const uint4*)buf;
  }
}

// ---- dis via split-bf16 MFMA; async global_load_lds staging ----
__global__ __launch_bounds__(256) void k_dism(const unsigned short* __restrict__ zhi,
                                              const unsigned short* __restrict__ zlo,
                                              float* __restrict__ pdis) {
  int q = blockIdx.x, sp = blockIdx.y, n = blockIdx.z;
  int bu = (q == 2) ? 1 : 0, bv = (q == 0) ? 0 : 1;
  int u0 = bu * 128, v0 = bv * 128;
  bool dg = (bu == bv);
  __shared__ unsigned short As[8 * 128 * 8];
  __shared__ unsigned short Bs[8 * 128 * 8];
  int tid = threadIdx.x, lane = tid & 63, wid = tid >> 6;
  int lr = lane & 15, lg = lane >> 4;
  f32x4 acc[2][8];
#pragma unroll
  for (int mi = 0; mi < 2; ++mi)
#pragma unroll
    for (int li = 0; li < 8; ++li) acc[mi][li] = (f32x4){0.f, 0.f, 0.f, 0.f};
  const int KCH = CT_ / DSPLIT_;  // 256
  int kbase = sp * KCH, kend = kbase + KCH;
  for (int kk = kbase; kk < kend; kk += 32) {
    int koct = kk >> 3;
    __syncthreads();
#pragma unroll
    for (int it = 0; it < 4; ++it) {
      int sl = tid + it * 256;
      int row = sl & 127, hs = sl >> 7;
      int slot = hs & 3, half = hs >> 2;
      const unsigned short* src = half ? zlo : zhi;
      size_t ob = ((size_t)n * 1024 + koct + slot) * ZR_;
      int ra = u0 + row; ra = ra > 207 ? 207 : ra;
      gload_lds16(src + (ob + ra) * 8, &As[sl * 8]);
      if (!dg) {
        int rb = v0 + row; rb = rb > 207 ? 207 : rb;
        gload_lds16(src + (ob + rb) * 8, &Bs[sl * 8]);
      }
    }
    __syncthreads();
    const unsigned short* Bp = dg ? As : Bs;
    short8v ah[2], al[2];
#pragma unroll
    for (int mi = 0; mi < 2; ++mi) {
      int r = wid * 32 + mi * 16 + lr;
      ah[mi] = *(const short8v*)&As[(lg * 128 + r) * 8];
      al[mi] = *(const short8v*)&As[((4 + lg) * 128 + r) * 8];
    }
#pragma unroll
    for (int li = 0; li < 8; ++li) {
      int rv = li * 16 + lr;
      short8v bh = *(const short8v*)&Bp[(lg * 128 + rv) * 8];
      short8v bl = *(const short8v*)&Bp[((4 + lg) * 128 + rv) * 8];
#pragma unroll
      for (int mi = 0; mi < 2; ++mi) {
        acc[mi][li] = __builtin_amdgcn_mfma_f32_16x16x32_bf16(ah[mi], bh, acc[mi][li], 0, 0, 0);
        acc[mi][li] = __builtin_amdgcn_mfma_f32_16x16x32_bf16(ah[mi], bl, acc[mi][li], 0, 0, 0);
        acc[mi][li] = __builtin_amdgcn_mfma_f32_16x16x32_bf16(al[mi], bh, acc[mi][li], 0, 0, 0);
      }
    }
  }
  float* pb = pdis + ((size_t)sp * N_ + n) * VV_;
#pragma unroll
  for (int mi = 0; mi < 2; ++mi) {
#pragma unroll
    for (int li = 0; li < 8; ++li) {
      int v = v0 + li * 16 + lr;
      if (v >= V_) continue;
#pragma unroll
      for (int rr = 0; rr < 4; ++rr) {
        int u = u0 + wid * 32 + mi * 16 + lg * 4 + rr;
        if (u >= V_) continue;
        float val = acc[mi][li][rr];
        pb[(size_t)u * V_ + v] = val;
        if (!dg) pb[(size_t)v * V_ + u] = val;
      }
    }
  }
}

// ---- fused partial-sum + wave-parallel top-3 ----
__global__ void k_topk2(const float* __restrict__ pdis, int* __restrict__ idx) {
  int r = blockIdx.x;
  int n = r / V_, u = r - n * V_;
  int lane = threadIdx.x;
  float m0 = -INFINITY, m1 = -INFINITY, m2 = -INFINITY;
  int i0 = 0x7fffffff, i1 = 0x7fffffff, i2 = 0x7fffffff;
#pragma unroll
  for (int g = 0; g < 4; ++g) {
    int v = g * 64 + lane;
    if (v >= V_) break;
    float a = 0.f;
#pragma unroll
    for (int sp = 0; sp < DSPLIT_; ++sp)
      a += pdis[((size_t)sp * N_ + n) * VV_ + (size_t)u * V_ + v];
    if (a > m0 || (a == m0 && v < i0)) {
      m2 = m1; i2 = i1; m1 = m0; i1 = i0; m0 = a; i0 = v;
    } else if (a > m1 || (a == m1 && v < i1)) {
      m2 = m1; i2 = i1; m1 = a; i1 = v;
    } else if (a > m2 || (a == m2 && v < i2)) {
      m2 = a; i2 = v;
    }
  }
#pragma unroll
  for (int msk = 1; msk < 64; msk <<= 1) {
    float o0 = __shfl_xor(m0, msk, 64), o1 = __shfl_xor(m1, msk, 64),
          o2 = __shfl_xor(m2, msk, 64);
    int p0 = __shfl_xor(i0, msk, 64), p1 = __shfl_xor(i1, msk, 64),
        p2 = __shfl_xor(i2, msk, 64);
    float ov[3] = {o0, o1, o2};
    int op[3] = {p0, p1, p2};
#pragma unroll
    for (int e = 0; e < 3; ++e) {
      float a = ov[e]; int v = op[e];
      if (a > m0 || (a == m0 && v < i0)) {
        m2 = m1; i2 = i1; m1 = m0; i1 = i0; m0 = a; i0 = v;
      } else if (a > m1 || (a == m1 && v < i1)) {
        m2 = m1; i2 = i1; m1 = a; i1 = v;
      } else if (a > m2 || (a == m2 && v < i2)) {
        m2 = a; i2 = v;
      }
    }
  }
  if (lane == 0) {
    idx[r * 3 + 0] = i0; idx[r * 3 + 1] = i1; idx[r * 3 + 2] = i2;
  }
}

// ---------------- w2 ----------------
__global__ void k_w2(const float* __restrict__ cm, const int* __restrict__ idx,
                     const float* __restrict__ tw, const float* __restrict__ tb,
                     const float* __restrict__ ckw, float* __restrict__ w2) {
  int r = blockIdx.x;
  int n = r / V_;
  int lane = threadIdx.x;
  __shared__ float mv[3][C_];
  const int* ib = idx + r * 3;
  int j0 = ib[0], j1 = ib[1], j2 = ib[2];
  const float* cmn = cm + (size_t)n * C_ * V_;
  for (int c = lane; c < C_; c += 64) {
    mv[0][c] = cmn[c * V_ + j0];
    mv[1][c] = cmn[c * V_ + j1];
    mv[2][c] = cmn[c * V_ + j2];
  }
  __syncthreads();
  float p[9];
#pragma unroll
  for (int gp = 0; gp < 9; ++gp) p[gp] = 0.f;
  for (int c = lane; c < C_; c += 64) {
#pragma unroll
    for (int g = 0; g < 3; ++g) {
      float m = mv[g][c];
#pragma unroll
      for (int pp = 0; pp < 3; ++pp) p[g * 3 + pp] += m * tw[(g * 3 + pp) * C_ + c];
    }
  }
#pragma unroll
  for (int off = 32; off >= 1; off >>= 1) {
#pragma unroll
    for (int gp = 0; gp < 9; ++gp) p[gp] += __shfl_down(p[gp], off, 64);
  }
  if (lane == 0) {
    float c0 = ckw[0], c1 = ckw[1], c2 = ckw[2];
#pragma unroll
    for (int g = 0; g < 3; ++g) {
      float m0 = p[g * 3 + 0] + tb[g * 3 + 0];
      float m1 = p[g * 3 + 1] + tb[g * 3 + 1];
      float m2 = p[g * 3 + 2] + tb[g * 3 + 2];
      float mx = fmaxf(m0, fmaxf(m1, m2));
      float e0 = expf(m0 - mx), e1 = expf(m1 - mx), e2 = expf(m2 - mx);
      float inv = 1.0f / (e0 + e1 + e2);
      w2[r * 3 + g] = (e0 * c0 + e1 * c1 + e2 * c2) * inv;
    }
  }
}

// ---- x1 producer -> [n][v][t][c] bf16 only ----
__global__ __launch_bounds__(256) void k_x1p(const float* __restrict__ x,
                                             const int* __restrict__ idx,
                                             const float* __restrict__ w2,
                                             const float* __restrict__ ckb,
                                             unsigned short* __restrict__ x1pb) {
  int t = blockIdx.x, ct = blockIdx.y, n = blockIdx.z;
  int c0 = ct * 32;
  __shared__ float Ts[32][209];
  __shared__ int iw[V_ * 3];
  __shared__ float ww[V_ * 3];
  int tid = threadIdx.x;
  const float* xb = x + ((size_t)n * C_ + c0) * TV_ + t * V_;
  for (int i = tid; i < 32 * V_; i += 256) {
    int c = i / V_, v = i - c * V_;
    Ts[c][v] = xb[(size_t)c * TV_ + v];
  }
  for (int i = tid; i < V_ * 3; i += 256) {
    iw[i] = idx[(size_t)n * V_ * 3 + i];
    ww[i] = w2[(size_t)n * V_ * 3 + i];
  }
  __syncthreads();
  float cb = ckb[0];
  for (int i = tid; i < 32 * V_; i += 256) {
    int v = i >> 5, cl = i & 31;
    int b = v * 3;
    float pooled = Ts[cl][iw[b]] * ww[b] + Ts[cl][iw[b + 1]] * ww[b + 1] +
                   Ts[cl][iw[b + 2]] * ww[b + 2] + cb;
    float val = fmaxf(pooled + Ts[cl][v], 0.f);
    x1pb[((size_t)(n * V_ + v) * T_ + t) * C_ + c0 + cl] = bf16rnd(val);
  }
}

// ---- MFMA GEMM: Y[l'][MS] = W@X (X=[l'][c] bf16), bf16 out, optional per-t pe bias ----
template <int MCH, int PEB, int STATS>
__global__ __launch_bounds__(256) void k_gmm2(const unsigned short* __restrict__ Wb,
                                              const unsigned short* __restrict__ Xp,
                                              const float* __restrict__ addv,
                                              unsigned short* __restrict__ Yh,
                                              float* __restrict__ part) {
  const int MS = MCH * 64;
  int l0 = blockIdx.x * 128, n = blockIdx.z;
  __shared__ unsigned short Xs[128 * 136];
  int tid = threadIdx.x, lane = tid & 63, wid = tid >> 6;
  int wm = wid >> 1, wl = wid & 1;
  int lr = lane & 15, lg = lane >> 4;
  const unsigned short* xb = Xp + ((size_t)n * TV_ + l0) * 128;
#pragma unroll
  for (int it = 0; it < 8; ++it) {
    int g = tid + it * 256;
    int row = g >> 4, ch = g & 15;
    *(uint4*)&Xs[row * 136 + ch * 8] = *(const uint4*)(xb + (size_t)row * 128 + ch * 8);
  }
  __syncthreads();
  for (int mc = 0; mc < MCH; ++mc) {
    short8v a[2][4];
#pragma unroll
    for (int mi = 0; mi < 2; ++mi) {
      int m = mc * 64 + wm * 32 + mi * 16 + lr;
#pragma unroll
      for (int ks = 0; ks < 4; ++ks)
        a[mi][ks] = *(const short8v*)(Wb + (size_t)m * 128 + ks * 32 + lg * 8);
    }
    f32x4 acc[2][4];
#pragma unroll
    for (int mi = 0; mi < 2; ++mi)
#pragma unroll
      for (int li = 0; li < 4; ++li) acc[mi][li] = (f32x4){0.f, 0.f, 0.f, 0.f};
#pragma unroll
    for (int ks = 0; ks < 4; ++ks) {
#pragma unroll
      for (int li = 0; li < 4; ++li) {
        short8v b = *(const short8v*)&Xs[(wl * 64 + li * 16 + lr) * 136 + ks * 32 + lg * 8];
#pragma unroll
        for (int mi = 0; mi < 2; ++mi)
          acc[mi][li] = __builtin_amdgcn_mfma_f32_16x16x32_bf16(a[mi][ks], b, acc[mi][li], 0, 0, 0);
      }
    }
    float st1[2][4] = {}, st2[2][4] = {};
#pragma unroll
    for (int mi = 0; mi < 2; ++mi)
#pragma unroll
      for (int li = 0; li < 4; ++li) {
        int lp = l0 + wl * 64 + li * 16 + lr;
        int m = mc * 64 + wm * 32 + mi * 16 + lg * 4;
        unsigned short b4[4];
#pragma unroll
        for (int r = 0; r < 4; ++r) {
          float val = acc[mi][li][r] +
                      (PEB ? addv[(m + r) * 64 + (lp & 63)] : addv[m + r]);
          if (STATS) { st1[mi][r] += val; st2[mi][r] += val * val; }
          b4[r] = bf16rnd(val);
        }
        *(uint2*)(Yh + ((size_t)n * TV_ + lp) * MS + m) = *(const uint2*)b4;
      }
    if (STATS) {
      int blk2 = ((n * gridDim.x + blockIdx.x) * 2 + wl) * 256;
#pragma unroll
      for (int mi = 0; mi < 2; ++mi)
#pragma unroll
        for (int r = 0; r < 4; ++r) {
          float a1 = st1[mi][r], a2 = st2[mi][r];
          a1 += __shfl_xor(a1, 1, 64); a2 += __shfl_xor(a2, 1, 64);
          a1 += __shfl_xor(a1, 2, 64); a2 += __shfl_xor(a2, 2, 64);
          a1 += __shfl_xor(a1, 4, 64); a2 += __shfl_xor(a2, 4, 64);
          a1 += __shfl_xor(a1, 8, 64); a2 += __shfl_xor(a2, 8, 64);
          if (lr == 0) {
            int m = mc * 64 + wm * 32 + mi * 16 + lg * 4 + r;
            part[blk2 + m] = a1;
            part[blk2 + 128 + m] = a2;
          }
        }
    }
  }
}

// ---- MFMA attention: qkv [l'][192]; attp[vs][n][h][t][q], vs 0..15 ----
__global__ __launch_bounds__(256) void k_attm(const unsigned short* __restrict__ qkv,
                                              float* __restrict__ attp) {
  int vs = blockIdx.x, h = blockIdx.y, n = blockIdx.z;
  __shared__ float buf[64 * 68];
  int tid = threadIdx.x, lane = tid & 63, wid = tid >> 6;
  int lr = lane & 15, lg = lane >> 4;
  f32x4 acc[4][4];
#pragma unroll
  for (int ti = 0; ti < 4; ++ti)
#pragma unroll
    for (int qi = 0; qi < 4; ++qi) acc[ti][qi] = (f32x4){0.f, 0.f, 0.f, 0.f};
  int vend = (vs + 1) * 13; if (vend > V_) vend = V_;
  for (int v = vs * 13 + wid; v < vend; v += 4) {
    const unsigned short* rb = qkv + ((size_t)n * TV_ + v * 64) * 192;
    short8v a[4], b[4];
#pragma unroll
    for (int ti = 0; ti < 4; ++ti)
      a[ti] = *(const short8v*)(rb + (size_t)(ti * 16 + lr) * 192 + h * 32 + lg * 8);
#pragma unroll
    for (int qi = 0; qi < 4; ++qi)
      b[qi] = *(const short8v*)(rb + (size_t)(qi * 16 + lr) * 192 + 96 + h * 32 + lg * 8);
#pragma unroll
    for (int ti = 0; ti < 4; ++ti)
#pragma unroll
      for (int qi = 0; qi < 4; ++qi)
        acc[ti][qi] = __builtin_amdgcn_mfma_f32_16x16x32_bf16(a[ti], b[qi], acc[ti][qi], 0, 0, 0);
  }
  if (wid == 0) {
#pragma unroll
    for (int ti = 0; ti < 4; ++ti)
#pragma unroll
      for (int qi = 0; qi < 4; ++qi)
#pragma unroll
        for (int r = 0; r < 4; ++r)
          buf[(ti * 16 + lg * 4 + r) * 68 + qi * 16 + lr] = acc[ti][qi][r];
  }
  __syncthreads();
  for (int w = 1; w < 4; ++w) {
    if (wid == w) {
#pragma unroll
      for (int ti = 0; ti < 4; ++ti)
#pragma unroll
        for (int qi = 0; qi < 4; ++qi)
#pragma unroll
          for (int r = 0; r < 4; ++r)
            buf[(ti * 16 + lg * 4 + r) * 68 + qi * 16 + lr] += acc[ti][qi][r];
    }
    __syncthreads();
  }
  float* ar = attp + (((size_t)vs * N_ + n) * H_ + h) * TT_;
  int t = tid >> 2, q0 = (tid & 3) * 16;
#pragma unroll
  for (int j = 0; j < 4; ++j)
    *(f32x4*)(ar + t * 64 + q0 + j * 4) = *(const f32x4*)&buf[t * 68 + q0 + j * 4];
}

// ---- attT[n][q][h*64+t] = bf16(tanh(sum_vs attp /6528)*alpha + att1s) ----
__global__ void k_attfin(const float* __restrict__ attp, const float* __restrict__ alphas,
                         const float* __restrict__ att1s, unsigned short* __restrict__ attT) {
  int i = blockIdx.x * blockDim.x + threadIdx.x;
  if (i >= N_ * H_ * TT_) return;
  int tt = i % TT_;
  int h = (i / TT_) % H_;
  int n = i / (H_ * TT_);
  float raw = 0.f;
#pragma unroll
  for (int cp = 0; cp < 16; ++cp)
    raw += attp[(((size_t)cp * N_ + n) * H_ + h) * TT_ + tt];
  int t = tt >> 6, q = tt & 63;
  float v = tanhf(raw * (1.0f / 6528.0f)) * alphas[h] + att1s[h * TT_ + tt];
  attT[(size_t)(n * 64 + q) * 192 + h * 64 + t] = bf16rnd(v);
}

// ---- fused Y3+comb, 512 threads / 2 v per block: wave-group vg={0,1} handles
//      v = blockIdx.x*2+vg with the verified v2 pipeline and its own Yv half. ----
__global__ __launch_bounds__(512) void k_fcomb(const unsigned short* __restrict__ x1pb,
                                               const unsigned short* __restrict__ w3b,
                                               const unsigned short* __restrict__ attT,
                                               const float* __restrict__ outb,
                                               unsigned short* __restrict__ preb,
                                               float* __restrict__ part) {
  int n = blockIdx.z;
  __shared__ unsigned short Yv[2][128 * 68];  // one 17.4 KB half per v-group
  int tid = threadIdx.x;
  int vg = tid >> 8, tid2 = tid & 255;
  int lane = tid & 63, wq = (tid >> 6) & 3;   // role within group
  int v = blockIdx.x * 2 + vg;
  int lr = lane & 15, lg = lane >> 4;
  unsigned short* Yc = Yv[vg];
  const unsigned short* xb = x1pb + ((size_t)(n * V_ + v) * T_) * 128;
  short8v bx[4][4];
#pragma unroll
  for (int ks = 0; ks < 4; ++ks)
#pragma unroll
    for (int li = 0; li < 4; ++li)
      bx[ks][li] = *(const short8v*)(xb + (size_t)(li * 16 + lr) * 128 + ks * 32 + lg * 8);
  f32x4 acc2[4][2];
#pragma unroll
  for (int mq = 0; mq < 4; ++mq)
#pragma unroll
    for (int oi = 0; oi < 2; ++oi) acc2[mq][oi] = (f32x4){0.f, 0.f, 0.f, 0.f};
  const unsigned short* ab = attT + (size_t)n * 64 * 192;
  for (int h = 0; h < H_; ++h) {
    short8v a1[2][4];
#pragma unroll
    for (int mi = 0; mi < 2; ++mi) {
      int m = wq * 32 + mi * 16 + lr;
#pragma unroll
      for (int ks = 0; ks < 4; ++ks)
        a1[mi][ks] = *(const short8v*)(w3b + ((size_t)(h * 128 + m)) * 128 + ks * 32 + lg * 8);
    }
    f32x4 acc1[2][4];
#pragma unroll
    for (int mi = 0; mi < 2; ++mi)
#pragma unroll
      for (int li = 0; li < 4; ++li) acc1[mi][li] = (f32x4){0.f, 0.f, 0.f, 0.f};
#pragma unroll
    for (int ks = 0; ks < 4; ++ks)
#pragma unroll
      for (int li = 0; li < 4; ++li)
#pragma unroll
        for (int mi = 0; mi < 2; ++mi)
          acc1[mi][li] = __builtin_amdgcn_mfma_f32_16x16x32_bf16(a1[mi][ks], bx[ks][li],
                                                                 acc1[mi][li], 0, 0, 0);
    __syncthreads();  // prior h's Yc reads (own group) done before overwrite
#pragma unroll
    for (int mi = 0; mi < 2; ++mi)
#pragma unroll
      for (int li = 0; li < 4; ++li) {
        int t = li * 16 + lr;
#pragma unroll
        for (int r = 0; r < 4; ++r) {
          int o = wq * 32 + mi * 16 + lg * 4 + r;
          Yc[o * 68 + t] = bf16rnd(acc1[mi][li][r]);
        }
      }
    __syncthreads();  // Yc complete
#pragma unroll
    for (int ks2 = 0; ks2 < 2; ++ks2) {
      short8v bY[2];
#pragma unroll
      for (int oi = 0; oi < 2; ++oi)
        bY[oi] = *(const short8v*)&Yc[(wq * 32 + oi * 16 + lr) * 68 + ks2 * 32 + lg * 8];
#pragma unroll
      for (int mq = 0; mq < 4; ++mq) {
        short8v a2 = *(const short8v*)(ab + (size_t)(mq * 16 + lr) * 192 + h * 64 + ks2 * 32 + lg * 8);
#pragma unroll
        for (int oi = 0; oi < 2; ++oi)
          acc2[mq][oi] = __builtin_amdgcn_mfma_f32_16x16x32_bf16(a2, bY[oi], acc2[mq][oi], 0, 0, 0);
      }
    }
  }
  __syncthreads();  // last acc2 reads done; Yc reusable as repack buffer
  float s1[2] = {0.f, 0.f}, s2[2] = {0.f, 0.f};
#pragma unroll
  for (int mq = 0; mq < 4; ++mq)
#pragma unroll
    for (int oi = 0; oi < 2; ++oi) {
      int o = wq * 32 + oi * 16 + lr;
      float bo = outb[o];
#pragma unroll
      for (int r = 0; r < 4; ++r) {
        int q = mq * 16 + lg * 4 + r;
        float val = acc2[mq][oi][r] + bo;
        s1[oi] += val; s2[oi] += val * val;
        Yc[q * 136 + o] = bf16rnd(val);  // [64][136] = 8704 shorts, exactly Yv half
      }
    }
  int blk = (n * V_ + v) * 256;
#pragma unroll
  for (int oi = 0; oi < 2; ++oi) {
    float a1 = s1[oi], a2v = s2[oi];
    a1 += __shfl_xor(a1, 16, 64); a2v += __shfl_xor(a2v, 16, 64);
    a1 += __shfl_xor(a1, 32, 64); a2v += __shfl_xor(a2v, 32, 64);
    if ((lane & 48) == 0) {
      int o = wq * 32 + oi * 16 + lr;
      part[blk + o] = a1;
      part[blk + 128 + o] = a2v;
    }
  }
  __syncthreads();
  unsigned short* ob2 = preb + ((size_t)(n * V_ + v) * T_) * 128;
#pragma unroll
  for (int it = 0; it < 4; ++it) {
    int g = tid2 + it * 256;
    int row = g >> 4, ch = g & 15;
    *(uint4*)(ob2 + (size_t)row * 128 + ch * 8) = *(const uint4*)&Yc[row * 136 + ch * 8];
  }
}

// ---- fold `count` stat partials -> ab[c]=a, ab[128+c]=b; grid 128 (c) ----
__global__ void k_bnab(const float* __restrict__ part, int count,
                       const float* __restrict__ g, const float* __restrict__ beta,
                       float* __restrict__ ab) {
  int c = blockIdx.x;
  int tid = threadIdx.x;
  float s1 = 0.f, s2 = 0.f;
  for (int b = tid; b < count; b += 256) {
    s1 += part[b * 256 + c];
    s2 += part[b * 256 + 128 + c];
  }
  __shared__ float r1[256], r2[256];
  r1[tid] = s1; r2[tid] = s2;
  __syncthreads();
  for (int off = 128; off >= 1; off >>= 1) {
    if (tid < off) { r1[tid] += r1[tid + off]; r2[tid] += r2[tid + off]; }
    __syncthreads();
  }
  if (tid == 0) {
    const float cnt = (float)(N_ * TV_);
    float mu = r1[0] / cnt;
    float rstd = rsqrtf(r2[0] / cnt - mu * mu + 1e-5f);
    float a = rstd * g[c];
    ab[c] = a;
    ab[128 + c] = beta[c] - mu * a;
  }
}

// ---- xs3pb = bf16(leaky(bn(preb)+x1pb)), elementwise [l'][c], all bf16 ----
__global__ void k_bnxt(const unsigned short* __restrict__ preb,
                       const unsigned short* __restrict__ x1pb,
                       const float* __restrict__ ab, unsigned short* __restrict__ xt) {
  __shared__ float sa[128], sb[128];
  int tid = threadIdx.x;
  if (tid < 128) { sa[tid] = ab[tid]; sb[tid] = ab[128 + tid]; }
  __syncthreads();
  const unsigned NU = (unsigned)(NCTV_ / 8);
  const uint4* p4 = (const uint4*)preb;
  const uint4* r4 = (const uint4*)x1pb;
  for (unsigned u = blockIdx.x * 256u + tid; u < NU; u += gridDim.x * 256u) {
    int c8 = (u & 15) * 8;
    uint4 pv = p4[u], rv = r4[u];
    const unsigned short* ps = (const unsigned short*)&pv;
    const unsigned short* rs = (const unsigned short*)&rv;
    unsigned short buf[8];
#pragma unroll
    for (int j = 0; j < 8; ++j) {
      float t = bf2f(ps[j]) * sa[c8 + j] + sb[c8 + j] + bf2f(rs[j]);
      buf[j] = bf16rnd(t > 0.f ? t : 0.1f * t);
    }
    *(uint4*)(xt + (size_t)u * 8) = *(const uint4*)buf;
  }
}

// ---- final: leaky(bn(preb)+x1pb), transpose [v][t][c] -> d_out [c][t][v] fp32 ----
__global__ __launch_bounds__(256) void k_bnfinal(const unsigned short* __restrict__ preb,
                                                 const unsigned short* __restrict__ x1pb,
                                                 const float* __restrict__ ab,
                                                 float* __restrict__ dout) {
  int ct = blockIdx.x, t = blockIdx.y, n = blockIdx.z;
  int c0 = ct * 32;
  __shared__ float Tf[V_][33];
  __shared__ float sa[32], sb[32];
  int tid = threadIdx.x;
  if (tid < 32) { sa[tid] = ab[c0 + tid]; sb[tid] = ab[128 + c0 + tid]; }
  __syncthreads();
  for (int i = tid; i < V_ * 4; i += 256) {
    int v = i >> 2, ch = i & 3;
    size_t a = ((size_t)(n * V_ + v) * T_ + t) * 128 + c0 + ch * 8;
    uint4 pv = *(const uint4*)(preb + a);
    uint4 rv = *(const uint4*)(x1pb + a);
    const unsigned short* ps = (const unsigned short*)&pv;
    const unsigned short* rs = (const unsigned short*)&rv;
#pragma unroll
    for (int j = 0; j < 8; ++j) {
      int cl = ch * 8 + j;
      float val = bf2f(ps[j]) * sa[cl] + sb[cl] + bf2f(rs[j]);
      Tf[v][cl] = val > 0.f ? val : 0.1f * val;
    }
  }
  __syncthreads();
  for (int i = tid; i < 32 * V_; i += 256) {
    int cl = i / V_, v = i - cl * V_;
    dout[((size_t)(n * C_ + c0 + cl) * T_ + t) * V_ + v] = Tf[v][cl];
  }
}

extern "C" void kernel_launch(void* const* d_in, const int* in_sizes, int n_in,
                              void* d_out, int out_size, void* d_ws, size_t ws_size,
                              hipStream_t stream) {
  (void)in_sizes; (void)n_in; (void)out_size; (void)ws_size;
  const float* x        = (const float*)d_in[0];
  const float* trans_w  = (const float*)d_in[1];
  const float* trans_b  = (const float*)d_in[2];
  const float* convk_w  = (const float*)d_in[3];
  const float* convk_b  = (const float*)d_in[4];
  const float* qkv_w    = (const float*)d_in[5];
  const float* qkv_b    = (const float*)d_in[6];
  const float* alphas   = (const float*)d_in[7];
  const float* att1s    = (const float*)d_in[8];
  const float* out_w    = (const float*)d_in[9];
  const float* out_b    = (const float*)d_in[10];
  const float* out_g    = (const float*)d_in[11];
  const float* out_beta = (const float*)d_in[12];
  const float* ff_w     = (const float*)d_in[13];
  const float* ff_b     = (const float*)d_in[14];
  const float* ff_g     = (const float*)d_in[15];
  const float* ff_beta  = (const float*)d_in[16];

  float* ws = (float*)d_ws;
  size_t off = 0;
  float* gq = ws + off; off += (size_t)N_ * O2_ * TV_ / 2 + NCTV_ / 2;
  float* pdis = gq;
  unsigned short* qkvb = (unsigned short*)gq;
  unsigned short* preb = (unsigned short*)(gq + (size_t)N_ * O2_ * TV_ / 2);
  float* sbuf = ws + off; off += (size_t)N_ * CT_;
  int*   idx  = (int*)(ws + off); off += (size_t)N_ * V_ * 3 + 4;
  float* cm   = ws + off; off += (size_t)N_ * C_ * V_;
  float* w2   = ws + off; off += (size_t)N_ * V_ * 3 + 4;
  float* attp = ws + off; off += (size_t)16 * N_ * H_ * TT_;
  unsigned short* attT = (unsigned short*)(ws + off); off += (size_t)N_ * 64 * 192 / 2;
  float* part = ws + off; off += (size_t)NBLK_ * 256;
  float* ab   = ws + off; off += 512;
  float* qpe  = ws + off; off += (size_t)O2_ * T_;
  unsigned short* wb = (unsigned short*)(ws + off); off += 704 * 128 / 2;
  const size_t ZEL = (size_t)N_ * 1024 * ZR_ * 8;
  unsigned short* zhi = (unsigned short*)(ws + off);
  unsigned short* zlo = zhi + ZEL;
  off += ZEL;
  unsigned short* x1pb  = zhi;
  unsigned short* xs3pb = zlo;
  float* dout = (float*)d_out;

  k_wprep<<<44, 256, 0, stream>>>(qkv_w, out_w, ff_w, wb);
  k_qkvpe<<<48, 256, 0, stream>>>(qkv_w, qkv_b, qpe);
  k_scale<<<(N_ * CT_ * 64) / 256, 256, 0, stream>>>(x, sbuf);
  k_zprep<<<dim3(128, 4, N_), 256, 0, stream>>>(x, sbuf, zhi, zlo, cm);
  k_dism<<<dim3(3, DSPLIT_, N_), 256, 0, stream>>>(zhi, zlo, pdis);
  k_topk2<<<N_ * V_, 64, 0, stream>>>(pdis, idx);
  k_w2<<<N_ * V_, 64, 0, stream>>>(cm, idx, trans_w, trans_b, convk_w, w2);
  k_x1p<<<dim3(64, 4, N_), 256, 0, stream>>>(x, idx, w2, convk_b, x1pb);

  // qkv = Wq@x1 + qkv_b + pe-bias -> qkvb bf16 [l'][192]
  k_gmm2<3, 1, 0><<<dim3(102, 1, N_), 256, 0, stream>>>(wb, x1pb, qpe, qkvb, nullptr);
  k_attm<<<dim3(16, H_, N_), 256, 0, stream>>>(qkvb, attp);
  k_attfin<<<384, 256, 0, stream>>>(attp, alphas, att1s, attT);

  // out_pre = fused (W3h@x1v) x attn -> preb bf16 [v][t][c], + BN stat partials
  k_fcomb<<<dim3(102, 1, N_), 512, 0, stream>>>(x1pb, wb + 192 * 128, attT, out_b, preb, part);

  k_bnab<<<128, 256, 0, stream>>>(part, NBLK_, out_g, out_beta, ab);
  k_bnxt<<<2048, 256, 0, stream>>>(preb, x1pb, ab, xs3pb);

  // ff_pre = Wff@xs3 + ff_b -> preb bf16 [l'][128] (overwrite), + BN stat partials
  k_gmm2<2, 0, 1><<<dim3(102, 1, N_), 256, 0, stream>>>(wb + 576 * 128, xs3pb, ff_b, preb, part);
  k_bnab<<<128, 256, 0, stream>>>(part, NBLK_, ff_g, ff_beta, ab + 256);
  k_bnfinal<<<dim3(4, 64, N_), 256, 0, stream>>>(preb, x1pb, ab + 256, dout);
}

// Round 13
// 311.123 us; speedup vs baseline: 1.0558x; 1.0558x over previous
//
#include <hip/hip_runtime.h>
#include <math.h>

#define N_ 8
#define C_ 128
#define T_ 64
#define V_ 204
#define H_ 3
#define QKD_ 32
#define O2_ 192            // 2*H*QKD
#define TV_ 13056          // T*V
#define CT_ 8192           // C*T
#define TT_ 4096           // T*T
#define VV_ 41616          // V*V
#define NCTV_ 13369344ull  // N*C*T*V
#define DSPLIT_ 32
#define ZR_ 208
#define NBLK_ 1632

typedef __attribute__((ext_vector_type(8))) short short8v;
typedef __attribute__((ext_vector_type(4))) float f32x4;

__device__ inline unsigned short bf16rnd(float f) {
  union { float f; unsigned u; } x; x.f = f;
  return (unsigned short)((x.u + 0x7FFFu + ((x.u >> 16) & 1u)) >> 16);
}
__device__ inline float bf2f(unsigned short u) {
  union { unsigned u; float f; } x; x.u = ((unsigned)u) << 16;
  return x.f;
}
// async global->LDS 16B (dest = wave-uniform base + lane*16; src per-lane)
__device__ inline void gload_lds16(const unsigned short* g, unsigned short* l) {
  __builtin_amdgcn_global_load_lds((const __attribute__((address_space(1))) void*)g,
                                   (__attribute__((address_space(3))) void*)l, 16, 0, 0);
}

// ---- weights -> bf16 rows [m][128]: qkv_wb(192) | w3b(384: [h][o]) | ff_wb(128) ----
__global__ void k_wprep(const float* __restrict__ qw, const float* __restrict__ ow,
                        const float* __restrict__ fw, unsigned short* __restrict__ wb) {
  int g = blockIdx.x * 256 + threadIdx.x;
  if (g >= 704 * 16) return;
  int row = g >> 4, ch = g & 15;
  const float* src;
  if (row < 192) src = qw + row * 128;
  else if (row < 576) { int r = row - 192; src = ow + (r & 127) * 384 + (r >> 7) * 128; }
  else src = fw + (row - 576) * 128;
  f32x4 a = *(const f32x4*)(src + ch * 8);
  f32x4 b = *(const f32x4*)(src + ch * 8 + 4);
  unsigned short buf[8];
  buf[0] = bf16rnd(a.x); buf[1] = bf16rnd(a.y); buf[2] = bf16rnd(a.z); buf[3] = bf16rnd(a.w);
  buf[4] = bf16rnd(b.x); buf[5] = bf16rnd(b.y); buf[6] = bf16rnd(b.z); buf[7] = bf16rnd(b.w);
  *(uint4*)(wb + (size_t)row * 128 + ch * 8) = *(const uint4*)buf;
}

// ---- qpe[m][t] = qkv_b[m] + sum_c qkv_w[m][c]*pe[c][t] ----
__global__ void k_qkvpe(const float* __restrict__ qw, const float* __restrict__ qb,
                        float* __restrict__ qpe) {
  __shared__ float pes[C_ * T_];
  int tid = threadIdx.x;
  for (int i = tid; i < C_ * T_; i += 256) {
    int t = i & 63, c = i >> 6;
    int j = c >> 1;
    float dv = expf((2.0f * j) * (-logf(10000.0f) / (float)C_));
    float ang = (float)t * dv;
    pes[i] = (c & 1) ? cosf(ang) : sinf(ang);
  }
  __syncthreads();
  int g = blockIdx.x * 256 + tid;
  int t = g & 63, m = g >> 6;
  float a = 0.f;
  for (int c = 0; c < C_; ++c) a += qw[m * C_ + c] * pes[c * T_ + t];
  qpe[g] = a + qb[m];
}

// ---------------- s[n,c,t] = 1/max(||x||,1e-12)^2 ----------------
__global__ void k_scale(const float* __restrict__ x, float* __restrict__ s) {
  int gid = blockIdx.x * blockDim.x + threadIdx.x;
  int w = gid >> 6, lane = gid & 63;
  if (w >= N_ * CT_) return;
  const f32x4* row = (const f32x4*)(x + (size_t)w * V_);
  float a = 0.f;
  for (int v4 = lane; v4 < 51; v4 += 64) {
    f32x4 t = row[v4];
    a += t.x * t.x + t.y * t.y + t.z * t.z + t.w * t.w;
  }
#pragma unroll
  for (int off = 32; off >= 1; off >>= 1) a += __shfl_down(a, off, 64);
  if (lane == 0) {
    float d = fmaxf(sqrtf(a), 1e-12f);
    s[w] = 1.0f / (d * d);
  }
}

// ---- Z-prep: fragment-major bf16 hi/lo + colmean ----
__global__ __launch_bounds__(256) void k_zprep(const float* __restrict__ x,
                                               const float* __restrict__ s,
                                               unsigned short* __restrict__ zhi,
                                               unsigned short* __restrict__ zlo,
                                               float* __restrict__ cm) {
  int kt = blockIdx.x, ut = blockIdx.y, n = blockIdx.z;
  int k0 = kt * 64, u0 = ut * 64;
  __shared__ float Ts[64][65];
  __shared__ float sq[64];
  int tid = threadIdx.x;
  int uu = tid & 63, kk = tid >> 6;
  int u = u0 + uu;
  bool uok = u < V_;
  const float* xb = x + (size_t)n * CT_ * V_;
#pragma unroll
  for (int it = 0; it < 16; ++it) {
    int kr = kk + it * 4;
    Ts[kr][uu] = uok ? xb[(size_t)(k0 + kr) * V_ + u] : 0.f;
  }
  if (tid < 64) sq[tid] = sqrtf(s[(size_t)n * CT_ + k0 + tid]);
  __syncthreads();
  if (tid < 64 && uok) {
    float a = 0.f;
    for (int t = 0; t < 64; ++t) a += Ts[t][tid];
    cm[((size_t)n * C_ + kt) * V_ + u] = a * (1.0f / 64.0f);
  }
#pragma unroll
  for (int it = 0; it < 4; ++it) {
    int sl = tid + it * 256;
    int u_l = sl & 63, oct = (sl >> 6) & 7, half = sl >> 9;
    int ug = u0 + u_l;
    if (ug >= ZR_) continue;
    unsigned short buf[8];
    if (ug < V_) {
#pragma unroll
      for (int j = 0; j < 8; ++j) {
        float z = Ts[oct * 8 + j][u_l] * sq[oct * 8 + j];
        unsigned short h = bf16rnd(z);
        buf[j] = half ? bf16rnd(z - bf2f(h)) : h;
      }
    } else {
#pragma unroll
      for (int j = 0; j < 8; ++j) buf[j] = 0;
    }
    unsigned short* dst = (half ? zlo : zhi) +
                          (((size_t)n * 1024 + kt * 8 + oct) * ZR_ + ug) * 8;
    *(uint4*)dst = *(const uint4*)buf;
  }
}

// ---- dis via split-bf16 MFMA; async global_load_lds staging ----
__global__ __launch_bounds__(256) void k_dism(const unsigned short* __restrict__ zhi,
                                              const unsigned short* __restrict__ zlo,
                                              float* __restrict__ pdis) {
  int q = blockIdx.x, sp = blockIdx.y, n = blockIdx.z;
  int bu = (q == 2) ? 1 : 0, bv = (q == 0) ? 0 : 1;
  int u0 = bu * 128, v0 = bv * 128;
  bool dg = (bu == bv);
  __shared__ unsigned short As[8 * 128 * 8];
  __shared__ unsigned short Bs[8 * 128 * 8];
  int tid = threadIdx.x, lane = tid & 63, wid = tid >> 6;
  int lr = lane & 15, lg = lane >> 4;
  f32x4 acc[2][8];
#pragma unroll
  for (int mi = 0; mi < 2; ++mi)
#pragma unroll
    for (int li = 0; li < 8; ++li) acc[mi][li] = (f32x4){0.f, 0.f, 0.f, 0.f};
  const int KCH = CT_ / DSPLIT_;  // 256
  int kbase = sp * KCH, kend = kbase + KCH;
  for (int kk = kbase; kk < kend; kk += 32) {
    int koct = kk >> 3;
    __syncthreads();
#pragma unroll
    for (int it = 0; it < 4; ++it) {
      int sl = tid + it * 256;
      int row = sl & 127, hs = sl >> 7;
      int slot = hs & 3, half = hs >> 2;
      const unsigned short* src = half ? zlo : zhi;
      size_t ob = ((size_t)n * 1024 + koct + slot) * ZR_;
      int ra = u0 + row; ra = ra > 207 ? 207 : ra;
      gload_lds16(src + (ob + ra) * 8, &As[sl * 8]);
      if (!dg) {
        int rb = v0 + row; rb = rb > 207 ? 207 : rb;
        gload_lds16(src + (ob + rb) * 8, &Bs[sl * 8]);
      }
    }
    __syncthreads();
    const unsigned short* Bp = dg ? As : Bs;
    short8v ah[2], al[2];
#pragma unroll
    for (int mi = 0; mi < 2; ++mi) {
      int r = wid * 32 + mi * 16 + lr;
      ah[mi] = *(const short8v*)&As[(lg * 128 + r) * 8];
      al[mi] = *(const short8v*)&As[((4 + lg) * 128 + r) * 8];
    }
#pragma unroll
    for (int li = 0; li < 8; ++li) {
      int rv = li * 16 + lr;
      short8v bh = *(const short8v*)&Bp[(lg * 128 + rv) * 8];
      short8v bl = *(const short8v*)&Bp[((4 + lg) * 128 + rv) * 8];
#pragma unroll
      for (int mi = 0; mi < 2; ++mi) {
        acc[mi][li] = __builtin_amdgcn_mfma_f32_16x16x32_bf16(ah[mi], bh, acc[mi][li], 0, 0, 0);
        acc[mi][li] = __builtin_amdgcn_mfma_f32_16x16x32_bf16(ah[mi], bl, acc[mi][li], 0, 0, 0);
        acc[mi][li] = __builtin_amdgcn_mfma_f32_16x16x32_bf16(al[mi], bh, acc[mi][li], 0, 0, 0);
      }
    }
  }
  float* pb = pdis + ((size_t)sp * N_ + n) * VV_;
#pragma unroll
  for (int mi = 0; mi < 2; ++mi) {
#pragma unroll
    for (int li = 0; li < 8; ++li) {
      int v = v0 + li * 16 + lr;
      if (v >= V_) continue;
#pragma unroll
      for (int rr = 0; rr < 4; ++rr) {
        int u = u0 + wid * 32 + mi * 16 + lg * 4 + rr;
        if (u >= V_) continue;
        float val = acc[mi][li][rr];
        pb[(size_t)u * V_ + v] = val;
        if (!dg) pb[(size_t)v * V_ + u] = val;
      }
    }
  }
}

// ---- fused partial-sum + wave-parallel top-3 ----
__global__ void k_topk2(const float* __restrict__ pdis, int* __restrict__ idx) {
  int r = blockIdx.x;
  int n = r / V_, u = r - n * V_;
  int lane = threadIdx.x;
  float m0 = -INFINITY, m1 = -INFINITY, m2 = -INFINITY;
  int i0 = 0x7fffffff, i1 = 0x7fffffff, i2 = 0x7fffffff;
#pragma unroll
  for (int g = 0; g < 4; ++g) {
    int v = g * 64 + lane;
    if (v >= V_) break;
    float a = 0.f;
#pragma unroll
    for (int sp = 0; sp < DSPLIT_; ++sp)
      a += pdis[((size_t)sp * N_ + n) * VV_ + (size_t)u * V_ + v];
    if (a > m0 || (a == m0 && v < i0)) {
      m2 = m1; i2 = i1; m1 = m0; i1 = i0; m0 = a; i0 = v;
    } else if (a > m1 || (a == m1 && v < i1)) {
      m2 = m1; i2 = i1; m1 = a; i1 = v;
    } else if (a > m2 || (a == m2 && v < i2)) {
      m2 = a; i2 = v;
    }
  }
#pragma unroll
  for (int msk = 1; msk < 64; msk <<= 1) {
    float o0 = __shfl_xor(m0, msk, 64), o1 = __shfl_xor(m1, msk, 64),
          o2 = __shfl_xor(m2, msk, 64);
    int p0 = __shfl_xor(i0, msk, 64), p1 = __shfl_xor(i1, msk, 64),
        p2 = __shfl_xor(i2, msk, 64);
    float ov[3] = {o0, o1, o2};
    int op[3] = {p0, p1, p2};
#pragma unroll
    for (int e = 0; e < 3; ++e) {
      float a = ov[e]; int v = op[e];
      if (a > m0 || (a == m0 && v < i0)) {
        m2 = m1; i2 = i1; m1 = m0; i1 = i0; m0 = a; i0 = v;
      } else if (a > m1 || (a == m1 && v < i1)) {
        m2 = m1; i2 = i1; m1 = a; i1 = v;
      } else if (a > m2 || (a == m2 && v < i2)) {
        m2 = a; i2 = v;
      }
    }
  }
  if (lane == 0) {
    idx[r * 3 + 0] = i0; idx[r * 3 + 1] = i1; idx[r * 3 + 2] = i2;
  }
}

// ---------------- w2 ----------------
__global__ void k_w2(const float* __restrict__ cm, const int* __restrict__ idx,
                     const float* __restrict__ tw, const float* __restrict__ tb,
                     const float* __restrict__ ckw, float* __restrict__ w2) {
  int r = blockIdx.x;
  int n = r / V_;
  int lane = threadIdx.x;
  __shared__ float mv[3][C_];
  const int* ib = idx + r * 3;
  int j0 = ib[0], j1 = ib[1], j2 = ib[2];
  const float* cmn = cm + (size_t)n * C_ * V_;
  for (int c = lane; c < C_; c += 64) {
    mv[0][c] = cmn[c * V_ + j0];
    mv[1][c] = cmn[c * V_ + j1];
    mv[2][c] = cmn[c * V_ + j2];
  }
  __syncthreads();
  float p[9];
#pragma unroll
  for (int gp = 0; gp < 9; ++gp) p[gp] = 0.f;
  for (int c = lane; c < C_; c += 64) {
#pragma unroll
    for (int g = 0; g < 3; ++g) {
      float m = mv[g][c];
#pragma unroll
      for (int pp = 0; pp < 3; ++pp) p[g * 3 + pp] += m * tw[(g * 3 + pp) * C_ + c];
    }
  }
#pragma unroll
  for (int off = 32; off >= 1; off >>= 1) {
#pragma unroll
    for (int gp = 0; gp < 9; ++gp) p[gp] += __shfl_down(p[gp], off, 64);
  }
  if (lane == 0) {
    float c0 = ckw[0], c1 = ckw[1], c2 = ckw[2];
#pragma unroll
    for (int g = 0; g < 3; ++g) {
      float m0 = p[g * 3 + 0] + tb[g * 3 + 0];
      float m1 = p[g * 3 + 1] + tb[g * 3 + 1];
      float m2 = p[g * 3 + 2] + tb[g * 3 + 2];
      float mx = fmaxf(m0, fmaxf(m1, m2));
      float e0 = expf(m0 - mx), e1 = expf(m1 - mx), e2 = expf(m2 - mx);
      float inv = 1.0f / (e0 + e1 + e2);
      w2[r * 3 + g] = (e0 * c0 + e1 * c1 + e2 * c2) * inv;
    }
  }
}

// ---- x1 producer -> [n][v][t][c] bf16 only ----
__global__ __launch_bounds__(256) void k_x1p(const float* __restrict__ x,
                                             const int* __restrict__ idx,
                                             const float* __restrict__ w2,
                                             const float* __restrict__ ckb,
                                             unsigned short* __restrict__ x1pb) {
  int t = blockIdx.x, ct = blockIdx.y, n = blockIdx.z;
  int c0 = ct * 32;
  __shared__ float Ts[32][209];
  __shared__ int iw[V_ * 3];
  __shared__ float ww[V_ * 3];
  int tid = threadIdx.x;
  const float* xb = x + ((size_t)n * C_ + c0) * TV_ + t * V_;
  for (int i = tid; i < 32 * V_; i += 256) {
    int c = i / V_, v = i - c * V_;
    Ts[c][v] = xb[(size_t)c * TV_ + v];
  }
  for (int i = tid; i < V_ * 3; i += 256) {
    iw[i] = idx[(size_t)n * V_ * 3 + i];
    ww[i] = w2[(size_t)n * V_ * 3 + i];
  }
  __syncthreads();
  float cb = ckb[0];
  for (int i = tid; i < 32 * V_; i += 256) {
    int v = i >> 5, cl = i & 31;
    int b = v * 3;
    float pooled = Ts[cl][iw[b]] * ww[b] + Ts[cl][iw[b + 1]] * ww[b + 1] +
                   Ts[cl][iw[b + 2]] * ww[b + 2] + cb;
    float val = fmaxf(pooled + Ts[cl][v], 0.f);
    x1pb[((size_t)(n * V_ + v) * T_ + t) * C_ + c0 + cl] = bf16rnd(val);
  }
}

// ---- MFMA GEMM: Y[l'][MS] = W@X (X=[l'][c] bf16), bf16 out, optional per-t pe bias ----
template <int MCH, int PEB, int STATS>
__global__ __launch_bounds__(256) void k_gmm2(const unsigned short* __restrict__ Wb,
                                              const unsigned short* __restrict__ Xp,
                                              const float* __restrict__ addv,
                                              unsigned short* __restrict__ Yh,
                                              float* __restrict__ part) {
  const int MS = MCH * 64;
  int l0 = blockIdx.x * 128, n = blockIdx.z;
  __shared__ unsigned short Xs[128 * 136];
  int tid = threadIdx.x, lane = tid & 63, wid = tid >> 6;
  int wm = wid >> 1, wl = wid & 1;
  int lr = lane & 15, lg = lane >> 4;
  const unsigned short* xb = Xp + ((size_t)n * TV_ + l0) * 128;
#pragma unroll
  for (int it = 0; it < 8; ++it) {
    int g = tid + it * 256;
    int row = g >> 4, ch = g & 15;
    *(uint4*)&Xs[row * 136 + ch * 8] = *(const uint4*)(xb + (size_t)row * 128 + ch * 8);
  }
  __syncthreads();
  for (int mc = 0; mc < MCH; ++mc) {
    short8v a[2][4];
#pragma unroll
    for (int mi = 0; mi < 2; ++mi) {
      int m = mc * 64 + wm * 32 + mi * 16 + lr;
#pragma unroll
      for (int ks = 0; ks < 4; ++ks)
        a[mi][ks] = *(const short8v*)(Wb + (size_t)m * 128 + ks * 32 + lg * 8);
    }
    f32x4 acc[2][4];
#pragma unroll
    for (int mi = 0; mi < 2; ++mi)
#pragma unroll
      for (int li = 0; li < 4; ++li) acc[mi][li] = (f32x4){0.f, 0.f, 0.f, 0.f};
#pragma unroll
    for (int ks = 0; ks < 4; ++ks) {
#pragma unroll
      for (int li = 0; li < 4; ++li) {
        short8v b = *(const short8v*)&Xs[(wl * 64 + li * 16 + lr) * 136 + ks * 32 + lg * 8];
#pragma unroll
        for (int mi = 0; mi < 2; ++mi)
          acc[mi][li] = __builtin_amdgcn_mfma_f32_16x16x32_bf16(a[mi][ks], b, acc[mi][li], 0, 0, 0);
      }
    }
    float st1[2][4] = {}, st2[2][4] = {};
#pragma unroll
    for (int mi = 0; mi < 2; ++mi)
#pragma unroll
      for (int li = 0; li < 4; ++li) {
        int lp = l0 + wl * 64 + li * 16 + lr;
        int m = mc * 64 + wm * 32 + mi * 16 + lg * 4;
        unsigned short b4[4];
#pragma unroll
        for (int r = 0; r < 4; ++r) {
          float val = acc[mi][li][r] +
                      (PEB ? addv[(m + r) * 64 + (lp & 63)] : addv[m + r]);
          if (STATS) { st1[mi][r] += val; st2[mi][r] += val * val; }
          b4[r] = bf16rnd(val);
        }
        *(uint2*)(Yh + ((size_t)n * TV_ + lp) * MS + m) = *(const uint2*)b4;
      }
    if (STATS) {
      int blk2 = ((n * gridDim.x + blockIdx.x) * 2 + wl) * 256;
#pragma unroll
      for (int mi = 0; mi < 2; ++mi)
#pragma unroll
        for (int r = 0; r < 4; ++r) {
          float a1 = st1[mi][r], a2 = st2[mi][r];
          a1 += __shfl_xor(a1, 1, 64); a2 += __shfl_xor(a2, 1, 64);
          a1 += __shfl_xor(a1, 2, 64); a2 += __shfl_xor(a2, 2, 64);
          a1 += __shfl_xor(a1, 4, 64); a2 += __shfl_xor(a2, 4, 64);
          a1 += __shfl_xor(a1, 8, 64); a2 += __shfl_xor(a2, 8, 64);
          if (lr == 0) {
            int m = mc * 64 + wm * 32 + mi * 16 + lg * 4 + r;
            part[blk2 + m] = a1;
            part[blk2 + 128 + m] = a2;
          }
        }
    }
  }
}

// ---- MFMA attention: qkv [l'][192]; attp[vs][n][h][t][q], vs 0..15 ----
__global__ __launch_bounds__(256) void k_attm(const unsigned short* __restrict__ qkv,
                                              float* __restrict__ attp) {
  int vs = blockIdx.x, h = blockIdx.y, n = blockIdx.z;
  __shared__ float buf[64 * 68];
  int tid = threadIdx.x, lane = tid & 63, wid = tid >> 6;
  int lr = lane & 15, lg = lane >> 4;
  f32x4 acc[4][4];
#pragma unroll
  for (int ti = 0; ti < 4; ++ti)
#pragma unroll
    for (int qi = 0; qi < 4; ++qi) acc[ti][qi] = (f32x4){0.f, 0.f, 0.f, 0.f};
  int vend = (vs + 1) * 13; if (vend > V_) vend = V_;
  for (int v = vs * 13 + wid; v < vend; v += 4) {
    const unsigned short* rb = qkv + ((size_t)n * TV_ + v * 64) * 192;
    short8v a[4], b[4];
#pragma unroll
    for (int ti = 0; ti < 4; ++ti)
      a[ti] = *(const short8v*)(rb + (size_t)(ti * 16 + lr) * 192 + h * 32 + lg * 8);
#pragma unroll
    for (int qi = 0; qi < 4; ++qi)
      b[qi] = *(const short8v*)(rb + (size_t)(qi * 16 + lr) * 192 + 96 + h * 32 + lg * 8);
#pragma unroll
    for (int ti = 0; ti < 4; ++ti)
#pragma unroll
      for (int qi = 0; qi < 4; ++qi)
        acc[ti][qi] = __builtin_amdgcn_mfma_f32_16x16x32_bf16(a[ti], b[qi], acc[ti][qi], 0, 0, 0);
  }
  if (wid == 0) {
#pragma unroll
    for (int ti = 0; ti < 4; ++ti)
#pragma unroll
      for (int qi = 0; qi < 4; ++qi)
#pragma unroll
        for (int r = 0; r < 4; ++r)
          buf[(ti * 16 + lg * 4 + r) * 68 + qi * 16 + lr] = acc[ti][qi][r];
  }
  __syncthreads();
  for (int w = 1; w < 4; ++w) {
    if (wid == w) {
#pragma unroll
      for (int ti = 0; ti < 4; ++ti)
#pragma unroll
        for (int qi = 0; qi < 4; ++qi)
#pragma unroll
          for (int r = 0; r < 4; ++r)
            buf[(ti * 16 + lg * 4 + r) * 68 + qi * 16 + lr] += acc[ti][qi][r];
    }
    __syncthreads();
  }
  float* ar = attp + (((size_t)vs * N_ + n) * H_ + h) * TT_;
  int t = tid >> 2, q0 = (tid & 3) * 16;
#pragma unroll
  for (int j = 0; j < 4; ++j)
    *(f32x4*)(ar + t * 64 + q0 + j * 4) = *(const f32x4*)&buf[t * 68 + q0 + j * 4];
}

// ---- attT[n][q][h*64+t] = bf16(tanh(sum_vs attp /6528)*alpha + att1s) ----
__global__ void k_attfin(const float* __restrict__ attp, const float* __restrict__ alphas,
                         const float* __restrict__ att1s, unsigned short* __restrict__ attT) {
  int i = blockIdx.x * blockDim.x + threadIdx.x;
  if (i >= N_ * H_ * TT_) return;
  int tt = i % TT_;
  int h = (i / TT_) % H_;
  int n = i / (H_ * TT_);
  float raw = 0.f;
#pragma unroll
  for (int cp = 0; cp < 16; ++cp)
    raw += attp[(((size_t)cp * N_ + n) * H_ + h) * TT_ + tt];
  int t = tt >> 6, q = tt & 63;
  float v = tanhf(raw * (1.0f / 6528.0f)) * alphas[h] + att1s[h * TT_ + tt];
  attT[(size_t)(n * 64 + q) * 192 + h * 64 + t] = bf16rnd(v);
}

// ---- fused Y3+comb v5: v2 decomposition, Yv traffic is WAVE-PRIVATE row stripes
//      (wave wid writes/reads rows [wid*32, wid*32+32) only) -> NO in-loop barriers;
//      single 17.4 KB Yv; 2 barriers total (pre-repack, pre-store). ----
__global__ __launch_bounds__(256) void k_fcomb(const unsigned short* __restrict__ x1pb,
                                               const unsigned short* __restrict__ w3b,
                                               const unsigned short* __restrict__ attT,
                                               const float* __restrict__ outb,
                                               unsigned short* __restrict__ preb,
                                               float* __restrict__ part) {
  int v = blockIdx.x, n = blockIdx.z;
  __shared__ unsigned short Yv[128 * 68];  // [o][t] padded; epilogue reuse as [q][136]
  int tid = threadIdx.x, lane = tid & 63, wid = tid >> 6;
  int lr = lane & 15, lg = lane >> 4;
  const unsigned short* xb = x1pb + ((size_t)(n * V_ + v) * T_) * 128;
  short8v bx[4][4];
#pragma unroll
  for (int ks = 0; ks < 4; ++ks)
#pragma unroll
    for (int li = 0; li < 4; ++li)
      bx[ks][li] = *(const short8v*)(xb + (size_t)(li * 16 + lr) * 128 + ks * 32 + lg * 8);
  f32x4 acc2[4][2];
#pragma unroll
  for (int mq = 0; mq < 4; ++mq)
#pragma unroll
    for (int oi = 0; oi < 2; ++oi) acc2[mq][oi] = (f32x4){0.f, 0.f, 0.f, 0.f};
  const unsigned short* ab = attT + (size_t)n * 64 * 192;
  for (int h = 0; h < H_; ++h) {
    short8v a1[2][4];
#pragma unroll
    for (int mi = 0; mi < 2; ++mi) {
      int m = wid * 32 + mi * 16 + lr;
#pragma unroll
      for (int ks = 0; ks < 4; ++ks)
        a1[mi][ks] = *(const short8v*)(w3b + ((size_t)(h * 128 + m)) * 128 + ks * 32 + lg * 8);
    }
    f32x4 acc1[2][4];
#pragma unroll
    for (int mi = 0; mi < 2; ++mi)
#pragma unroll
      for (int li = 0; li < 4; ++li) acc1[mi][li] = (f32x4){0.f, 0.f, 0.f, 0.f};
#pragma unroll
    for (int ks = 0; ks < 4; ++ks)
#pragma unroll
      for (int li = 0; li < 4; ++li)
#pragma unroll
        for (int mi = 0; mi < 2; ++mi)
          acc1[mi][li] = __builtin_amdgcn_mfma_f32_16x16x32_bf16(a1[mi][ks], bx[ks][li],
                                                                 acc1[mi][li], 0, 0, 0);
    // write own row stripe (wave-private; same-wave ordering via lgkmcnt)
#pragma unroll
    for (int mi = 0; mi < 2; ++mi)
#pragma unroll
      for (int li = 0; li < 4; ++li) {
        int t = li * 16 + lr;
#pragma unroll
        for (int r = 0; r < 4; ++r) {
          int o = wid * 32 + mi * 16 + lg * 4 + r;
          Yv[o * 68 + t] = bf16rnd(acc1[mi][li][r]);
        }
      }
    // comb: read own row stripe only
#pragma unroll
    for (int ks2 = 0; ks2 < 2; ++ks2) {
      short8v bY[2];
#pragma unroll
      for (int oi = 0; oi < 2; ++oi)
        bY[oi] = *(const short8v*)&Yv[(wid * 32 + oi * 16 + lr) * 68 + ks2 * 32 + lg * 8];
#pragma unroll
      for (int mq = 0; mq < 4; ++mq) {
        short8v a2 = *(const short8v*)(ab + (size_t)(mq * 16 + lr) * 192 + h * 64 + ks2 * 32 + lg * 8);
#pragma unroll
        for (int oi = 0; oi < 2; ++oi)
          acc2[mq][oi] = __builtin_amdgcn_mfma_f32_16x16x32_bf16(a2, bY[oi], acc2[mq][oi], 0, 0, 0);
      }
    }
  }
  __syncthreads();  // all waves' h-loop Yv ops done before cross-stripe repack
  // epilogue: bias + stats + repack [q][136] into Yv (8704 shorts exactly)
  float s1[2] = {0.f, 0.f}, s2[2] = {0.f, 0.f};
#pragma unroll
  for (int mq = 0; mq < 4; ++mq)
#pragma unroll
    for (int oi = 0; oi < 2; ++oi) {
      int o = wid * 32 + oi * 16 + lr;
      float bo = outb[o];
#pragma unroll
      for (int r = 0; r < 4; ++r) {
        int q = mq * 16 + lg * 4 + r;
        float val = acc2[mq][oi][r] + bo;
        s1[oi] += val; s2[oi] += val * val;
        Yv[q * 136 + o] = bf16rnd(val);
      }
    }
  int blk = (n * V_ + v) * 256;
#pragma unroll
  for (int oi = 0; oi < 2; ++oi) {
    float a1 = s1[oi], a2v = s2[oi];
    a1 += __shfl_xor(a1, 16, 64); a2v += __shfl_xor(a2v, 16, 64);
    a1 += __shfl_xor(a1, 32, 64); a2v += __shfl_xor(a2v, 32, 64);
    if ((lane & 48) == 0) {
      int o = wid * 32 + oi * 16 + lr;
      part[blk + o] = a1;
      part[blk + 128 + o] = a2v;
    }
  }
  __syncthreads();  // repack complete before cross-wave coalesced store
  unsigned short* ob2 = preb + ((size_t)(n * V_ + v) * T_) * 128;
#pragma unroll
  for (int it = 0; it < 4; ++it) {
    int g = tid + it * 256;
    int row = g >> 4, ch = g & 15;
    *(uint4*)(ob2 + (size_t)row * 128 + ch * 8) = *(const uint4*)&Yv[row * 136 + ch * 8];
  }
}

// ---- fold `count` stat partials -> ab[c]=a, ab[128+c]=b; grid 128 (c) ----
__global__ void k_bnab(const float* __restrict__ part, int count,
                       const float* __restrict__ g, const float* __restrict__ beta,
                       float* __restrict__ ab) {
  int c = blockIdx.x;
  int tid = threadIdx.x;
  float s1 = 0.f, s2 = 0.f;
  for (int b = tid; b < count; b += 256) {
    s1 += part[b * 256 + c];
    s2 += part[b * 256 + 128 + c];
  }
  __shared__ float r1[256], r2[256];
  r1[tid] = s1; r2[tid] = s2;
  __syncthreads();
  for (int off = 128; off >= 1; off >>= 1) {
    if (tid < off) { r1[tid] += r1[tid + off]; r2[tid] += r2[tid + off]; }
    __syncthreads();
  }
  if (tid == 0) {
    const float cnt = (float)(N_ * TV_);
    float mu = r1[0] / cnt;
    float rstd = rsqrtf(r2[0] / cnt - mu * mu + 1e-5f);
    float a = rstd * g[c];
    ab[c] = a;
    ab[128 + c] = beta[c] - mu * a;
  }
}

// ---- xs3pb = bf16(leaky(bn(preb)+x1pb)), elementwise [l'][c], all bf16 ----
__global__ void k_bnxt(const unsigned short* __restrict__ preb,
                       const unsigned short* __restrict__ x1pb,
                       const float* __restrict__ ab, unsigned short* __restrict__ xt) {
  __shared__ float sa[128], sb[128];
  int tid = threadIdx.x;
  if (tid < 128) { sa[tid] = ab[tid]; sb[tid] = ab[128 + tid]; }
  __syncthreads();
  const unsigned NU = (unsigned)(NCTV_ / 8);
  const uint4* p4 = (const uint4*)preb;
  const uint4* r4 = (const uint4*)x1pb;
  for (unsigned u = blockIdx.x * 256u + tid; u < NU; u += gridDim.x * 256u) {
    int c8 = (u & 15) * 8;
    uint4 pv = p4[u], rv = r4[u];
    const unsigned short* ps = (const unsigned short*)&pv;
    const unsigned short* rs = (const unsigned short*)&rv;
    unsigned short buf[8];
#pragma unroll
    for (int j = 0; j < 8; ++j) {
      float t = bf2f(ps[j]) * sa[c8 + j] + sb[c8 + j] + bf2f(rs[j]);
      buf[j] = bf16rnd(t > 0.f ? t : 0.1f * t);
    }
    *(uint4*)(xt + (size_t)u * 8) = *(const uint4*)buf;
  }
}

// ---- final: leaky(bn(preb)+x1pb), transpose [v][t][c] -> d_out [c][t][v] fp32 ----
__global__ __launch_bounds__(256) void k_bnfinal(const unsigned short* __restrict__ preb,
                                                 const unsigned short* __restrict__ x1pb,
                                                 const float* __restrict__ ab,
                                                 float* __restrict__ dout) {
  int ct = blockIdx.x, t = blockIdx.y, n = blockIdx.z;
  int c0 = ct * 32;
  __shared__ float Tf[V_][33];
  __shared__ float sa[32], sb[32];
  int tid = threadIdx.x;
  if (tid < 32) { sa[tid] = ab[c0 + tid]; sb[tid] = ab[128 + c0 + tid]; }
  __syncthreads();
  for (int i = tid; i < V_ * 4; i += 256) {
    int v = i >> 2, ch = i & 3;
    size_t a = ((size_t)(n * V_ + v) * T_ + t) * 128 + c0 + ch * 8;
    uint4 pv = *(const uint4*)(preb + a);
    uint4 rv = *(const uint4*)(x1pb + a);
    const unsigned short* ps = (const unsigned short*)&pv;
    const unsigned short* rs = (const unsigned short*)&rv;
#pragma unroll
    for (int j = 0; j < 8; ++j) {
      int cl = ch * 8 + j;
      float val = bf2f(ps[j]) * sa[cl] + sb[cl] + bf2f(rs[j]);
      Tf[v][cl] = val > 0.f ? val : 0.1f * val;
    }
  }
  __syncthreads();
  for (int i = tid; i < 32 * V_; i += 256) {
    int cl = i / V_, v = i - cl * V_;
    dout[((size_t)(n * C_ + c0 + cl) * T_ + t) * V_ + v] = Tf[v][cl];
  }
}

extern "C" void kernel_launch(void* const* d_in, const int* in_sizes, int n_in,
                              void* d_out, int out_size, void* d_ws, size_t ws_size,
                              hipStream_t stream) {
  (void)in_sizes; (void)n_in; (void)out_size; (void)ws_size;
  const float* x        = (const float*)d_in[0];
  const float* trans_w  = (const float*)d_in[1];
  const float* trans_b  = (const float*)d_in[2];
  const float* convk_w  = (const float*)d_in[3];
  const float* convk_b  = (const float*)d_in[4];
  const float* qkv_w    = (const float*)d_in[5];
  const float* qkv_b    = (const float*)d_in[6];
  const float* alphas   = (const float*)d_in[7];
  const float* att1s    = (const float*)d_in[8];
  const float* out_w    = (const float*)d_in[9];
  const float* out_b    = (const float*)d_in[10];
  const float* out_g    = (const float*)d_in[11];
  const float* out_beta = (const float*)d_in[12];
  const float* ff_w     = (const float*)d_in[13];
  const float* ff_b     = (const float*)d_in[14];
  const float* ff_g     = (const float*)d_in[15];
  const float* ff_beta  = (const float*)d_in[16];

  float* ws = (float*)d_ws;
  size_t off = 0;
  float* gq = ws + off; off += (size_t)N_ * O2_ * TV_ / 2 + NCTV_ / 2;
  float* pdis = gq;
  unsigned short* qkvb = (unsigned short*)gq;
  unsigned short* preb = (unsigned short*)(gq + (size_t)N_ * O2_ * TV_ / 2);
  float* sbuf = ws + off; off += (size_t)N_ * CT_;
  int*   idx  = (int*)(ws + off); off += (size_t)N_ * V_ * 3 + 4;
  float* cm   = ws + off; off += (size_t)N_ * C_ * V_;
  float* w2   = ws + off; off += (size_t)N_ * V_ * 3 + 4;
  float* attp = ws + off; off += (size_t)16 * N_ * H_ * TT_;
  unsigned short* attT = (unsigned short*)(ws + off); off += (size_t)N_ * 64 * 192 / 2;
  float* part = ws + off; off += (size_t)NBLK_ * 256;
  float* ab   = ws + off; off += 512;
  float* qpe  = ws + off; off += (size_t)O2_ * T_;
  unsigned short* wb = (unsigned short*)(ws + off); off += 704 * 128 / 2;
  const size_t ZEL = (size_t)N_ * 1024 * ZR_ * 8;
  unsigned short* zhi = (unsigned short*)(ws + off);
  unsigned short* zlo = zhi + ZEL;
  off += ZEL;
  unsigned short* x1pb  = zhi;
  unsigned short* xs3pb = zlo;
  float* dout = (float*)d_out;

  k_wprep<<<44, 256, 0, stream>>>(qkv_w, out_w, ff_w, wb);
  k_qkvpe<<<48, 256, 0, stream>>>(qkv_w, qkv_b, qpe);
  k_scale<<<(N_ * CT_ * 64) / 256, 256, 0, stream>>>(x, sbuf);
  k_zprep<<<dim3(128, 4, N_), 256, 0, stream>>>(x, sbuf, zhi, zlo, cm);
  k_dism<<<dim3(3, DSPLIT_, N_), 256, 0, stream>>>(zhi, zlo, pdis);
  k_topk2<<<N_ * V_, 64, 0, stream>>>(pdis, idx);
  k_w2<<<N_ * V_, 64, 0, stream>>>(cm, idx, trans_w, trans_b, convk_w, w2);
  k_x1p<<<dim3(64, 4, N_), 256, 0, stream>>>(x, idx, w2, convk_b, x1pb);

  // qkv = Wq@x1 + qkv_b + pe-bias -> qkvb bf16 [l'][192]
  k_gmm2<3, 1, 0><<<dim3(102, 1, N_), 256, 0, stream>>>(wb, x1pb, qpe, qkvb, nullptr);
  k_attm<<<dim3(16, H_, N_), 256, 0, stream>>>(qkvb, attp);
  k_attfin<<<384, 256, 0, stream>>>(attp, alphas, att1s, attT);

  // out_pre = fused (W3h@x1v) x attn -> preb bf16 [v][t][c], + BN stat partials
  k_fcomb<<<dim3(204, 1, N_), 256, 0, stream>>>(x1pb, wb + 192 * 128, attT, out_b, preb, part);

  k_bnab<<<128, 256, 0, stream>>>(part, NBLK_, out_g, out_beta, ab);
  k_bnxt<<<2048, 256, 0, stream>>>(preb, x1pb, ab, xs3pb);

  // ff_pre = Wff@xs3 + ff_b -> preb bf16 [l'][128] (overwrite), + BN stat partials
  k_gmm2<2, 0, 1><<<dim3(102, 1, N_), 256, 0, stream>>>(wb + 576 * 128, xs3pb, ff_b, preb, part);
  k_bnab<<<128, 256, 0, stream>>>(part, NBLK_, ff_g, ff_beta, ab + 256);
  k_bnfinal<<<dim3(4, 64, N_), 256, 0, stream>>>(preb, x1pb, ab + 256, dout);
}